// Round 5
// baseline (336.419 us; speedup 1.0000x reference)
//
#include <hip/hip_runtime.h>

typedef _Float16 f16;
typedef __attribute__((ext_vector_type(8))) _Float16 f16x8;
typedef __attribute__((ext_vector_type(4))) _Float16 f16x4;
typedef __attribute__((ext_vector_type(4))) float f32x4;

#define DEVINL __device__ __forceinline__

DEVINL void gload16(const void* g, void* l) {
  __builtin_amdgcn_global_load_lds(
      (const __attribute__((address_space(1))) void*)g,
      (__attribute__((address_space(3))) void*)l, 16, 0, 0);
}

DEVINL f32x4 mfma16(f16x8 a, f16x8 b, f32x4 c) {
  return __builtin_amdgcn_mfma_f32_16x16x32_f16(a, b, c, 0, 0, 0);
}

// ---------------------------------------------------------------- converts
__global__ __launch_bounds__(256) void convert_k(const float* __restrict__ src,
                                                 f16* __restrict__ dst, int n) {
  int i = (blockIdx.x * 256 + threadIdx.x) * 4;
  if (i + 3 < n) {
    f32x4 v = *(const f32x4*)(src + i);
    f16x4 o = {(f16)v[0], (f16)v[1], (f16)v[2], (f16)v[3]};
    *(f16x4*)(dst + i) = o;
  }
}

// x (B,768,2048) f32 -> Xt (B,2048,768) f16   (64x64 tiles via padded LDS)
__global__ __launch_bounds__(256) void transpose_x(const float* __restrict__ x,
                                                   f16* __restrict__ xt) {
  __shared__ __attribute__((aligned(16))) f16 T[64 * 66];
  const int b = blockIdx.z, c0 = blockIdx.y * 64, n0 = blockIdx.x * 64;
  const int t = threadIdx.x;
  const float* xb = x + (size_t)b * 768 * 2048;
#pragma unroll
  for (int r = 0; r < 4; ++r) {
    int chunk = r * 256 + t;
    int row = chunk >> 4, c4 = (chunk & 15) * 4;
    f32x4 v = *(const f32x4*)&xb[(size_t)(c0 + row) * 2048 + n0 + c4];
#pragma unroll
    for (int e = 0; e < 4; ++e) T[row * 66 + c4 + e] = (f16)v[e];
  }
  __syncthreads();
  f16* xtb = xt + (size_t)b * 2048 * 768;
  int n = t >> 2, cp = (t & 3) * 16;
  __attribute__((aligned(16))) f16 vals[16];
#pragma unroll
  for (int j = 0; j < 16; ++j) vals[j] = T[(cp + j) * 66 + n];
  *(f16x8*)&xtb[(size_t)(n0 + n) * 768 + c0 + cp] = *(const f16x8*)&vals[0];
  *(f16x8*)&xtb[(size_t)(n0 + n) * 768 + c0 + cp + 8] = *(const f16x8*)&vals[8];
}

// ---------------------------------------------------------------- GEMM
// C[m0+128][n0+128] = A(M,768) @ Bt(2048,768)^T   per batch z.
// kind==1: fp32 direct store to outp (B,768,2048)
// kind==0: m0<1536 -> transposed f16 store into qkt (B,2048,1536)
//          m0>=1536 -> direct f16 store into vbuf (B,768,2048)
__global__ __launch_bounds__(256, 2)
void gemm_kernel(const f16* __restrict__ A, const f16* __restrict__ Bt,
                 f16* __restrict__ qkt, f16* __restrict__ vbuf,
                 float* __restrict__ outp, int kind) {
  constexpr int K = 768;
  const int b = blockIdx.z;
  const int n0 = blockIdx.x * 128;
  const int m0 = blockIdx.y * 128;
  const int t = threadIdx.x;
  const int lane = t & 63, w = t >> 6, g = lane >> 4, lo = lane & 15;
  const int wm = (w >> 1) * 64, wn = (w & 1) * 64;

  __shared__ __attribute__((aligned(16))) f16 smem[16384];
  f16* As = smem;          // [128 m][64 k], chunk-swizzled (c8 ^= row&7)
  f16* Bs = smem + 8192;   // [128 n][64 k], same swizzle

  const f16* Ab = A + (size_t)m0 * K;
  const f16* Bb = Bt + (size_t)b * 2048 * K + (size_t)n0 * K;

  const f32x4 zf = {0.f, 0.f, 0.f, 0.f};
  f32x4 acc[4][4];
#pragma unroll
  for (int i = 0; i < 4; ++i)
#pragma unroll
    for (int j = 0; j < 4; ++j) acc[i][j] = zf;

  for (int kt = 0; kt < K; kt += 64) {
    __syncthreads();
#pragma unroll
    for (int r = 0; r < 4; ++r) {
      int chunk = r * 256 + t;
      int row = chunk >> 3;
      int c8 = (chunk & 7) ^ (row & 7);
      gload16(Ab + (size_t)row * K + kt + c8 * 8, As + chunk * 8);
    }
#pragma unroll
    for (int r = 0; r < 4; ++r) {
      int chunk = r * 256 + t;
      int row = chunk >> 3;
      int c8 = (chunk & 7) ^ (row & 7);
      gload16(Bb + (size_t)row * K + kt + c8 * 8, Bs + chunk * 8);
    }
    __syncthreads();
#pragma unroll
    for (int kk = 0; kk < 2; ++kk) {
      f16x8 af[4], bfr[4];
#pragma unroll
      for (int i = 0; i < 4; ++i) {
        int row = wm + i * 16 + lo;
        af[i] = *(const f16x8*)&As[row * 64 + (((kk * 4 + g) ^ (row & 7)) * 8)];
      }
#pragma unroll
      for (int j = 0; j < 4; ++j) {
        int col = wn + j * 16 + lo;
        bfr[j] = *(const f16x8*)&Bs[col * 64 + (((kk * 4 + g) ^ (col & 7)) * 8)];
      }
#pragma unroll
      for (int i = 0; i < 4; ++i)
#pragma unroll
        for (int j = 0; j < 4; ++j)
          acc[i][j] = mfma16(af[i], bfr[j], acc[i][j]);
    }
  }

  if (kind == 1) {
    float* Cb = outp + (size_t)b * 768 * 2048;
#pragma unroll
    for (int i = 0; i < 4; ++i) {
      int row = m0 + wm + i * 16 + g * 4;
#pragma unroll
      for (int j = 0; j < 4; ++j) {
        int col = n0 + wn + j * 16 + lo;
#pragma unroll
        for (int r2 = 0; r2 < 4; ++r2)
          Cb[(size_t)(row + r2) * 2048 + col] = acc[i][j][r2];
      }
    }
  } else if (m0 >= 1536) {
    f16* Vb = vbuf + (size_t)b * 768 * 2048;
#pragma unroll
    for (int i = 0; i < 4; ++i) {
      int row = m0 - 1536 + wm + i * 16 + g * 4;
#pragma unroll
      for (int j = 0; j < 4; ++j) {
        int col = n0 + wn + j * 16 + lo;
#pragma unroll
        for (int r2 = 0; r2 < 4; ++r2)
          Vb[(size_t)(row + r2) * 2048 + col] = (f16)acc[i][j][r2];
      }
    }
  } else {
    // transpose-store via LDS: QKt[b][n0+n][m0 + m] = C[m][n]
    __syncthreads();
    f16* T = smem;  // [128 n][128 m], chunk16-swizzled (c ^= n&15)
#pragma unroll
    for (int i = 0; i < 4; ++i)
#pragma unroll
      for (int j = 0; j < 4; ++j) {
        int nl = wn + j * 16 + lo;
#pragma unroll
        for (int r2 = 0; r2 < 4; ++r2) {
          int ml = wm + i * 16 + g * 4 + r2;
          T[nl * 128 + (((ml >> 3) ^ (nl & 15)) * 8) + (ml & 7)] =
              (f16)acc[i][j][r2];
        }
      }
    __syncthreads();
    f16* Qb = qkt + (size_t)b * 2048 * 1536;
    int n = t >> 1, half = t & 1;
#pragma unroll
    for (int c = 0; c < 8; ++c) {
      int chunk = half * 8 + c;
      f16x8 v = *(const f16x8*)&T[n * 128 + ((chunk ^ (n & 15)) * 8)];
      *(f16x8*)&Qb[(size_t)(n0 + n) * 1536 + m0 + chunk * 8] = v;
    }
  }
}

// ---------------------------------------------------------------- attention
// qkt (B,2048,1536): cols 0..767 = Q (h*64+d), 768..1535 = K.  vbuf (B,768,2048).
// ctxt (B,2048,768) f16 output (n-major for the out-proj GEMM).
__global__ __launch_bounds__(256, 2)
void attn_kernel(const f16* __restrict__ qkt, const f16* __restrict__ vbuf,
                 const int* __restrict__ mask, f16* __restrict__ ctxt) {
  const int bh = blockIdx.y;
  const int b = bh / 12, h = bh % 12;
  const int n0 = blockIdx.x * 128;
  const int t = threadIdx.x;
  const int lane = t & 63, w = t >> 6, g = lane >> 4, lo = lane & 15;

  __shared__ __attribute__((aligned(16))) f16 Kt[8192];      // [128 m][64 d] swz
  __shared__ __attribute__((aligned(16))) f16 Vs[8192];      // [64 d][128 m] swz
  __shared__ __attribute__((aligned(16))) f16 Ps[4][4096];   // per-wave [32 q][128 m] swz
  __shared__ int mask_s[2048];

  const f16* qb = qkt + (size_t)b * 2048 * 1536;
#pragma unroll
  for (int r = 0; r < 8; ++r) mask_s[r * 256 + t] = mask[b * 2048 + r * 256 + t];

  // Q fragments straight from global (n-major rows), fold 1/sqrt(64)=0.125 in.
  f16x8 qa[2][2];
#pragma unroll
  for (int fm = 0; fm < 2; ++fm)
#pragma unroll
    for (int kk = 0; kk < 2; ++kk) {
      f16x8 v = *(const f16x8*)&qb[(size_t)(n0 + w * 32 + fm * 16 + lo) * 1536 +
                                   h * 64 + kk * 32 + g * 8];
#pragma unroll
      for (int e = 0; e < 8; ++e) v[e] = (f16)((float)v[e] * 0.125f);
      qa[fm][kk] = v;
    }

  const f32x4 zf = {0.f, 0.f, 0.f, 0.f};
  f32x4 oacc[2][4];
  float mrun[2][4], lrun[2][4];
#pragma unroll
  for (int fm = 0; fm < 2; ++fm) {
#pragma unroll
    for (int fd = 0; fd < 4; ++fd) oacc[fm][fd] = zf;
#pragma unroll
    for (int r2 = 0; r2 < 4; ++r2) { mrun[fm][r2] = -3e38f; lrun[fm][r2] = 0.f; }
  }

  const f16* kb_g = qb + 768 + h * 64;
  const f16* vb_g = vbuf + (size_t)b * 768 * 2048 + (size_t)(h * 64) * 2048;
  f16* psw = &Ps[w][0];

  for (int mt = 0; mt < 16; ++mt) {
    const int m0 = mt * 128;
    __syncthreads();
#pragma unroll
    for (int r = 0; r < 4; ++r) {  // K tile: rows m, 8 d-chunks, src pre-swizzled
      int chunk = r * 256 + t;
      int row = chunk >> 3;
      int c8 = (chunk & 7) ^ (row & 7);
      gload16(kb_g + (size_t)(m0 + row) * 1536 + c8 * 8, Kt + chunk * 8);
    }
#pragma unroll
    for (int r = 0; r < 4; ++r) {  // V tile: rows d, 16 m-chunks, src pre-swizzled
      int chunk = r * 256 + t;
      int d = chunk >> 4;
      int c16 = (chunk & 15) ^ (d & 15);
      gload16(vb_g + (size_t)d * 2048 + m0 + c16 * 8, Vs + chunk * 8);
    }
    __syncthreads();

    // S = (Q/8) K^T : per wave 2 q-frags x 8 m-frags
    f32x4 sacc[2][8];
#pragma unroll
    for (int fm = 0; fm < 2; ++fm)
#pragma unroll
      for (int fn = 0; fn < 8; ++fn) sacc[fm][fn] = zf;
#pragma unroll
    for (int kk = 0; kk < 2; ++kk)
#pragma unroll
      for (int fn = 0; fn < 8; ++fn) {
        int m = fn * 16 + lo;
        f16x8 kf = *(const f16x8*)&Kt[m * 64 + (((kk * 4 + g) ^ (m & 7)) * 8)];
        sacc[0][fn] = mfma16(qa[0][kk], kf, sacc[0][fn]);
        sacc[1][fn] = mfma16(qa[1][kk], kf, sacc[1][fn]);
      }

    // mask key positions
#pragma unroll
    for (int fn = 0; fn < 8; ++fn) {
      if (mask_s[m0 + fn * 16 + lo] == 0) {
#pragma unroll
        for (int fm = 0; fm < 2; ++fm)
#pragma unroll
          for (int r2 = 0; r2 < 4; ++r2) sacc[fm][fn][r2] = -1e30f;
      }
    }

    // online softmax (rows owned in-lane: q = fm*16 + g*4 + r2)
#pragma unroll
    for (int fm = 0; fm < 2; ++fm)
#pragma unroll
      for (int r2 = 0; r2 < 4; ++r2) {
        float mx = sacc[fm][0][r2];
#pragma unroll
        for (int fn = 1; fn < 8; ++fn) mx = fmaxf(mx, sacc[fm][fn][r2]);
#pragma unroll
        for (int off = 1; off < 16; off <<= 1)
          mx = fmaxf(mx, __shfl_xor(mx, off, 64));
        float mnew = fmaxf(mrun[fm][r2], mx);
        float alpha = __expf(mrun[fm][r2] - mnew);
        mrun[fm][r2] = mnew;
        float rs = 0.f;
        int q = fm * 16 + g * 4 + r2;
        int qs = q & 15;
#pragma unroll
        for (int fn = 0; fn < 8; ++fn) {
          float p = __expf(sacc[fm][fn][r2] - mnew);
          rs += p;
          int m = fn * 16 + lo;
          psw[q * 128 + (((m >> 3) ^ qs) * 8) + (m & 7)] = (f16)p;
        }
#pragma unroll
        for (int off = 1; off < 16; off <<= 1) rs += __shfl_xor(rs, off, 64);
        lrun[fm][r2] = lrun[fm][r2] * alpha + rs;
        // BUGFIX (r4): alpha is per-row (r2); scale ONLY component r2.
        // Previous code scaled the whole f32x4 inside the r2 loop ->
        // every component got the product of all four alphas.
#pragma unroll
        for (int fd = 0; fd < 4; ++fd) oacc[fm][fd][r2] *= alpha;
      }

    // O += P @ V^T
#pragma unroll
    for (int kk = 0; kk < 4; ++kk) {
      f16x8 pa[2], vf[4];
#pragma unroll
      for (int fm = 0; fm < 2; ++fm) {
        int q = fm * 16 + lo;
        pa[fm] = *(const f16x8*)&psw[q * 128 + (((kk * 4 + g) ^ (q & 15)) * 8)];
      }
#pragma unroll
      for (int fd = 0; fd < 4; ++fd) {
        int d = fd * 16 + lo;
        vf[fd] = *(const f16x8*)&Vs[d * 128 + (((kk * 4 + g) ^ (d & 15)) * 8)];
      }
#pragma unroll
      for (int fm = 0; fm < 2; ++fm)
#pragma unroll
        for (int fd = 0; fd < 4; ++fd)
          oacc[fm][fd] = mfma16(pa[fm], vf[fd], oacc[fm][fd]);
    }
  }

  // epilogue: O /= l, transpose via LDS, store n-major ctxt rows
  __syncthreads();
  f16* T2 = Kt;  // [128 q][64 d] swz
#pragma unroll
  for (int fm = 0; fm < 2; ++fm)
#pragma unroll
    for (int fd = 0; fd < 4; ++fd)
#pragma unroll
      for (int r2 = 0; r2 < 4; ++r2) {
        int q = w * 32 + fm * 16 + g * 4 + r2;
        int d = fd * 16 + lo;
        float v = oacc[fm][fd][r2] / lrun[fm][r2];
        T2[q * 64 + (((d >> 3) ^ (q & 7)) * 8) + (d & 7)] = (f16)v;
      }
  __syncthreads();
  f16* cb = ctxt + (size_t)b * 2048 * 768;
  int qrow = t >> 1, half = t & 1;
#pragma unroll
  for (int c = 0; c < 4; ++c) {
    int c8 = half * 4 + c;
    f16x8 v = *(const f16x8*)&T2[qrow * 64 + ((c8 ^ (qrow & 7)) * 8)];
    *(f16x8*)&cb[(size_t)(n0 + qrow) * 768 + h * 64 + c8 * 8] = v;
  }
}

// ---------------------------------------------------------------- launch
// ws total = 27,525,120 f16 = 52.5 MiB. Ctxt aliases Xt (dead after GEMM1).
extern "C" void kernel_launch(void* const* d_in, const int* in_sizes, int n_in,
                              void* d_out, int out_size, void* d_ws,
                              size_t ws_size, hipStream_t stream) {
  const float* x  = (const float*)d_in[0];
  const float* Wq = (const float*)d_in[1];
  const float* Wk = (const float*)d_in[2];
  const float* Wv = (const float*)d_in[3];
  const float* Wo = (const float*)d_in[4];
  const int* mask = (const int*)d_in[5];
  float* out = (float*)d_out;

  f16* Xt   = (f16*)d_ws;            // 6291456  (B,2048,768) -- reused as Ctxt
  f16* Wcat = Xt + 6291456;          // 1769472  (2304,768)  Wq|Wk|Wv rows
  f16* Wob  = Wcat + 1769472;        // 589824   (768,768)
  f16* QKt  = Wob + 589824;          // 12582912 (B,2048,1536)
  f16* Vbuf = QKt + 12582912;        // 6291456  (B,768,2048)
  f16* Ctxt = Xt;                    // alias    (B,2048,768)

  convert_k<<<576, 256, 0, stream>>>(Wq, Wcat, 589824);
  convert_k<<<576, 256, 0, stream>>>(Wk, Wcat + 589824, 589824);
  convert_k<<<576, 256, 0, stream>>>(Wv, Wcat + 1179648, 589824);
  convert_k<<<576, 256, 0, stream>>>(Wo, Wob, 589824);
  transpose_x<<<dim3(32, 12, 4), 256, 0, stream>>>(x, Xt);
  gemm_kernel<<<dim3(16, 18, 4), 256, 0, stream>>>(Wcat, Xt, QKt, Vbuf, nullptr, 0);
  attn_kernel<<<dim3(16, 48), 256, 0, stream>>>(QKt, Vbuf, mask, Ctxt);
  gemm_kernel<<<dim3(16, 6, 4), 256, 0, stream>>>(Wob, Ctxt, nullptr, nullptr, out, 1);
}

// Round 6
// 259.199 us; speedup vs baseline: 1.2979x; 1.2979x over previous
//
#include <hip/hip_runtime.h>

typedef _Float16 f16;
typedef __attribute__((ext_vector_type(8))) _Float16 f16x8;
typedef __attribute__((ext_vector_type(4))) _Float16 f16x4;
typedef __attribute__((ext_vector_type(4))) float f32x4;

#define DEVINL __device__ __forceinline__

DEVINL void gload16(const void* g, void* l) {
  __builtin_amdgcn_global_load_lds(
      (const __attribute__((address_space(1))) void*)g,
      (__attribute__((address_space(3))) void*)l, 16, 0, 0);
}

DEVINL f32x4 mfma16(f16x8 a, f16x8 b, f32x4 c) {
  return __builtin_amdgcn_mfma_f32_16x16x32_f16(a, b, c, 0, 0, 0);
}

// ---------------------------------------------------------------- converts
__global__ __launch_bounds__(256) void convert_k(const float* __restrict__ src,
                                                 f16* __restrict__ dst, int n) {
  int i = (blockIdx.x * 256 + threadIdx.x) * 4;
  if (i + 3 < n) {
    f32x4 v = *(const f32x4*)(src + i);
    f16x4 o = {(f16)v[0], (f16)v[1], (f16)v[2], (f16)v[3]};
    *(f16x4*)(dst + i) = o;
  }
}

// x (B,768,2048) f32 -> Xt (B,2048,768) f16   (64x64 tiles via padded LDS)
__global__ __launch_bounds__(256) void transpose_x(const float* __restrict__ x,
                                                   f16* __restrict__ xt) {
  __shared__ __attribute__((aligned(16))) f16 T[64 * 66];
  const int b = blockIdx.z, c0 = blockIdx.y * 64, n0 = blockIdx.x * 64;
  const int t = threadIdx.x;
  const float* xb = x + (size_t)b * 768 * 2048;
#pragma unroll
  for (int r = 0; r < 4; ++r) {
    int chunk = r * 256 + t;
    int row = chunk >> 4, c4 = (chunk & 15) * 4;
    f32x4 v = *(const f32x4*)&xb[(size_t)(c0 + row) * 2048 + n0 + c4];
#pragma unroll
    for (int e = 0; e < 4; ++e) T[row * 66 + c4 + e] = (f16)v[e];
  }
  __syncthreads();
  f16* xtb = xt + (size_t)b * 2048 * 768;
  int n = t >> 2, cp = (t & 3) * 16;
  __attribute__((aligned(16))) f16 vals[16];
#pragma unroll
  for (int j = 0; j < 16; ++j) vals[j] = T[(cp + j) * 66 + n];
  *(f16x8*)&xtb[(size_t)(n0 + n) * 768 + c0 + cp] = *(const f16x8*)&vals[0];
  *(f16x8*)&xtb[(size_t)(n0 + n) * 768 + c0 + cp + 8] = *(const f16x8*)&vals[8];
}

// ---------------------------------------------------------------- GEMM
// C[m0+128][n0+128] = A(M,768) @ Bt(2048,768)^T   per batch z.
// kind==1: fp32 direct store to outp (B,768,2048)
// kind==0: m0<1536 -> transposed f16 store into qkt (B,2048,1536)
//          m0>=1536 -> direct f16 store into vbuf (B,768,2048)
__global__ __launch_bounds__(256, 2)
void gemm_kernel(const f16* __restrict__ A, const f16* __restrict__ Bt,
                 f16* __restrict__ qkt, f16* __restrict__ vbuf,
                 float* __restrict__ outp, int kind) {
  constexpr int K = 768;
  const int b = blockIdx.z;
  const int n0 = blockIdx.x * 128;
  const int m0 = blockIdx.y * 128;
  const int t = threadIdx.x;
  const int lane = t & 63, w = t >> 6, g = lane >> 4, lo = lane & 15;
  const int wm = (w >> 1) * 64, wn = (w & 1) * 64;

  __shared__ __attribute__((aligned(16))) f16 smem[16384];
  f16* As = smem;          // [128 m][64 k], chunk-swizzled (c8 ^= row&7)
  f16* Bs = smem + 8192;   // [128 n][64 k], same swizzle

  const f16* Ab = A + (size_t)m0 * K;
  const f16* Bb = Bt + (size_t)b * 2048 * K + (size_t)n0 * K;

  const f32x4 zf = {0.f, 0.f, 0.f, 0.f};
  f32x4 acc[4][4];
#pragma unroll
  for (int i = 0; i < 4; ++i)
#pragma unroll
    for (int j = 0; j < 4; ++j) acc[i][j] = zf;

  for (int kt = 0; kt < K; kt += 64) {
    __syncthreads();
#pragma unroll
    for (int r = 0; r < 4; ++r) {
      int chunk = r * 256 + t;
      int row = chunk >> 3;
      int c8 = (chunk & 7) ^ (row & 7);
      gload16(Ab + (size_t)row * K + kt + c8 * 8, As + chunk * 8);
    }
#pragma unroll
    for (int r = 0; r < 4; ++r) {
      int chunk = r * 256 + t;
      int row = chunk >> 3;
      int c8 = (chunk & 7) ^ (row & 7);
      gload16(Bb + (size_t)row * K + kt + c8 * 8, Bs + chunk * 8);
    }
    __syncthreads();
#pragma unroll
    for (int kk = 0; kk < 2; ++kk) {
      f16x8 af[4], bfr[4];
#pragma unroll
      for (int i = 0; i < 4; ++i) {
        int row = wm + i * 16 + lo;
        af[i] = *(const f16x8*)&As[row * 64 + (((kk * 4 + g) ^ (row & 7)) * 8)];
      }
#pragma unroll
      for (int j = 0; j < 4; ++j) {
        int col = wn + j * 16 + lo;
        bfr[j] = *(const f16x8*)&Bs[col * 64 + (((kk * 4 + g) ^ (col & 7)) * 8)];
      }
#pragma unroll
      for (int i = 0; i < 4; ++i)
#pragma unroll
        for (int j = 0; j < 4; ++j)
          acc[i][j] = mfma16(af[i], bfr[j], acc[i][j]);
    }
  }

  if (kind == 1) {
    float* Cb = outp + (size_t)b * 768 * 2048;
#pragma unroll
    for (int i = 0; i < 4; ++i) {
      int row = m0 + wm + i * 16 + g * 4;
#pragma unroll
      for (int j = 0; j < 4; ++j) {
        int col = n0 + wn + j * 16 + lo;
#pragma unroll
        for (int r2 = 0; r2 < 4; ++r2)
          Cb[(size_t)(row + r2) * 2048 + col] = acc[i][j][r2];
      }
    }
  } else if (m0 >= 1536) {
    f16* Vb = vbuf + (size_t)b * 768 * 2048;
#pragma unroll
    for (int i = 0; i < 4; ++i) {
      int row = m0 - 1536 + wm + i * 16 + g * 4;
#pragma unroll
      for (int j = 0; j < 4; ++j) {
        int col = n0 + wn + j * 16 + lo;
#pragma unroll
        for (int r2 = 0; r2 < 4; ++r2)
          Vb[(size_t)(row + r2) * 2048 + col] = (f16)acc[i][j][r2];
      }
    }
  } else {
    // transpose-store via LDS: QKt[b][n0+n][m0 + m] = C[m][n]
    __syncthreads();
    f16* T = smem;  // [128 n][128 m], chunk16-swizzled (c ^= n&15)
#pragma unroll
    for (int i = 0; i < 4; ++i)
#pragma unroll
      for (int j = 0; j < 4; ++j) {
        int nl = wn + j * 16 + lo;
#pragma unroll
        for (int r2 = 0; r2 < 4; ++r2) {
          int ml = wm + i * 16 + g * 4 + r2;
          T[nl * 128 + (((ml >> 3) ^ (nl & 15)) * 8) + (ml & 7)] =
              (f16)acc[i][j][r2];
        }
      }
    __syncthreads();
    f16* Qb = qkt + (size_t)b * 2048 * 1536;
    int n = t >> 1, half = t & 1;
#pragma unroll
    for (int c = 0; c < 8; ++c) {
      int chunk = half * 8 + c;
      f16x8 v = *(const f16x8*)&T[n * 128 + ((chunk ^ (n & 15)) * 8)];
      *(f16x8*)&Qb[(size_t)(n0 + n) * 1536 + m0 + chunk * 8] = v;
    }
  }
}

// ---------------------------------------------------------------- attention
// Swapped-operand flash attention (round 5 rewrite):
//   S^T = mfma(K, Q): sacc[fm][fn][reg] = S[q=fm*16+lo][m=fn*16+g*4+reg]
//   -> alpha/m/l are per-(fm) lane-local scalars, oacc *= alpha is a legal
//      vector op, P-quad writes are contiguous (ds_write_b64).
//   O^T = mfma(V, P^T): oacc[fm][fd][reg] = O[q=fm*16+lo][d=fd*16+g*4+reg].
// exp2 domain: Q pre-scaled by 0.125*log2e; mask as additive f16 bias -60000
// (exp2 underflows to exactly 0). LDS 52KB -> 3 blocks/CU (grid = 3/CU, no tail).
__global__ __launch_bounds__(256, 3)
void attn_kernel(const f16* __restrict__ qkt, const f16* __restrict__ vbuf,
                 const int* __restrict__ mask, f16* __restrict__ ctxt) {
  const int bh = blockIdx.y;
  const int b = bh / 12, h = bh % 12;
  const int n0 = blockIdx.x * 128;
  const int t = threadIdx.x;
  const int lane = t & 63, w = t >> 6, g = lane >> 4, lo = lane & 15;

  __shared__ __attribute__((aligned(16))) f16 Kt[8192];    // [128 m][64 d] swz
  __shared__ __attribute__((aligned(16))) f16 Vs[8192];    // [64 d][128 m] swz
  __shared__ __attribute__((aligned(16))) f16 Ps[8192];    // 4 waves x [32 q][64 m] swz
  __shared__ __attribute__((aligned(16))) f16 bias_s[2048];

  const f16* qb = qkt + (size_t)b * 2048 * 1536;
  const int* mb = mask + b * 2048;
#pragma unroll
  for (int r = 0; r < 8; ++r) {
    int i = r * 256 + t;
    bias_s[i] = (f16)(mb[i] ? 0.f : -60000.f);
  }

  // Q fragments from global; fold 0.125 * log2(e) so exp() -> v_exp_f32.
  constexpr float QS = 0.125f * 1.44269504088896f;
  f16x8 qa[2][2];
#pragma unroll
  for (int fm = 0; fm < 2; ++fm)
#pragma unroll
    for (int kk = 0; kk < 2; ++kk) {
      f16x8 v = *(const f16x8*)&qb[(size_t)(n0 + w * 32 + fm * 16 + lo) * 1536 +
                                   h * 64 + kk * 32 + g * 8];
#pragma unroll
      for (int e = 0; e < 8; ++e) v[e] = (f16)((float)v[e] * QS);
      qa[fm][kk] = v;
    }

  const f32x4 zf = {0.f, 0.f, 0.f, 0.f};
  f32x4 oacc[2][4];
  float mrun[2], lrun[2];
#pragma unroll
  for (int fm = 0; fm < 2; ++fm) {
#pragma unroll
    for (int fd = 0; fd < 4; ++fd) oacc[fm][fd] = zf;
    mrun[fm] = -3e38f;
    lrun[fm] = 0.f;
  }

  const f16* kb_g = qb + 768 + h * 64;
  const f16* vb_g = vbuf + (size_t)b * 768 * 2048 + (size_t)(h * 64) * 2048;
  f16* psw = &Ps[w * 2048];  // [32 q][64 m], chunk(8xf16)-swizzled c ^= q&7

  for (int mt = 0; mt < 16; ++mt) {
    const int m0 = mt * 128;
    __syncthreads();
#pragma unroll
    for (int r = 0; r < 4; ++r) {  // K tile: rows m, 8 d-chunks, src pre-swizzled
      int chunk = r * 256 + t;
      int row = chunk >> 3;
      int c8 = (chunk & 7) ^ (row & 7);
      gload16(kb_g + (size_t)(m0 + row) * 1536 + c8 * 8, Kt + chunk * 8);
    }
#pragma unroll
    for (int r = 0; r < 4; ++r) {  // V tile: rows d, 16 m-chunks, src pre-swizzled
      int chunk = r * 256 + t;
      int d = chunk >> 4;
      int c16 = (chunk & 15) ^ (d & 15);
      gload16(vb_g + (size_t)d * 2048 + m0 + c16 * 8, Vs + chunk * 8);
    }
    __syncthreads();

    // S^T = K Q^T (exp2 domain)
    f32x4 sacc[2][8];
#pragma unroll
    for (int fm = 0; fm < 2; ++fm)
#pragma unroll
      for (int fn = 0; fn < 8; ++fn) sacc[fm][fn] = zf;
#pragma unroll
    for (int kk = 0; kk < 2; ++kk)
#pragma unroll
      for (int fn = 0; fn < 8; ++fn) {
        int m = fn * 16 + lo;
        f16x8 kf = *(const f16x8*)&Kt[m * 64 + (((kk * 4 + g) ^ (m & 7)) * 8)];
        sacc[0][fn] = mfma16(kf, qa[0][kk], sacc[0][fn]);
        sacc[1][fn] = mfma16(kf, qa[1][kk], sacc[1][fn]);
      }

    // mask bias: m = fn*16 + g*4 + reg  -> contiguous f16x4 per (fn)
#pragma unroll
    for (int fn = 0; fn < 8; ++fn) {
      f16x4 b4 = *(const f16x4*)&bias_s[m0 + fn * 16 + g * 4];
      f32x4 ba = {(float)b4[0], (float)b4[1], (float)b4[2], (float)b4[3]};
      sacc[0][fn] += ba;
      sacc[1][fn] += ba;
    }

    // online softmax: q = fm*16 + lo is lane-local; reduce only across g.
    f16x4 p16[2][8];
#pragma unroll
    for (int fm = 0; fm < 2; ++fm) {
      f32x4 vm = sacc[fm][0];
#pragma unroll
      for (int fn = 1; fn < 8; ++fn)
#pragma unroll
        for (int r = 0; r < 4; ++r) vm[r] = fmaxf(vm[r], sacc[fm][fn][r]);
      float mx = fmaxf(fmaxf(vm[0], vm[1]), fmaxf(vm[2], vm[3]));
      mx = fmaxf(mx, __shfl_xor(mx, 16, 64));
      mx = fmaxf(mx, __shfl_xor(mx, 32, 64));
      float mnew = fmaxf(mrun[fm], mx);
      float alpha = __builtin_amdgcn_exp2f(mrun[fm] - mnew);
      mrun[fm] = mnew;
      f32x4 vs_ = zf;
#pragma unroll
      for (int fn = 0; fn < 8; ++fn) {
        f32x4 pv;
#pragma unroll
        for (int r = 0; r < 4; ++r)
          pv[r] = __builtin_amdgcn_exp2f(sacc[fm][fn][r] - mnew);
        vs_ += pv;
        f16x4 ph = {(f16)pv[0], (f16)pv[1], (f16)pv[2], (f16)pv[3]};
        p16[fm][fn] = ph;
      }
      float rs = (vs_[0] + vs_[1]) + (vs_[2] + vs_[3]);
      rs += __shfl_xor(rs, 16, 64);
      rs += __shfl_xor(rs, 32, 64);
      lrun[fm] = lrun[fm] * alpha + rs;
#pragma unroll
      for (int fd = 0; fd < 4; ++fd) oacc[fm][fd] *= alpha;
    }

    // O^T += V P^T, two 64-wide phases through the per-wave P buffer
#pragma unroll
    for (int ph = 0; ph < 2; ++ph) {
#pragma unroll
      for (int fm = 0; fm < 2; ++fm) {
        int q32 = fm * 16 + lo;
        int sw = q32 & 7;
#pragma unroll
        for (int fi = 0; fi < 4; ++fi) {
          int cq = fi * 2 + (g >> 1);
          *(f16x4*)&psw[q32 * 64 + ((cq ^ sw) * 8) + (g & 1) * 4] =
              p16[fm][ph * 4 + fi];
        }
      }
      // within-wave LDS ops are ordered; no barrier needed
#pragma unroll
      for (int kkl = 0; kkl < 2; ++kkl) {
        int kk = ph * 2 + kkl;
        f16x8 pa[2], vf[4];
#pragma unroll
        for (int fm = 0; fm < 2; ++fm) {
          int q32 = fm * 16 + lo;
          pa[fm] =
              *(const f16x8*)&psw[q32 * 64 + (((kkl * 4 + g) ^ (q32 & 7)) * 8)];
        }
#pragma unroll
        for (int fd = 0; fd < 4; ++fd) {
          int d = fd * 16 + lo;
          vf[fd] = *(const f16x8*)&Vs[d * 128 + (((kk * 4 + g) ^ (d & 15)) * 8)];
        }
#pragma unroll
        for (int fm = 0; fm < 2; ++fm)
#pragma unroll
          for (int fd = 0; fd < 4; ++fd)
            oacc[fm][fd] = mfma16(vf[fd], pa[fm], oacc[fm][fd]);
      }
    }
  }

  // epilogue: O /= l; oacc quads are d-contiguous -> f16x4 LDS writes
  __syncthreads();
  f16* T2 = Kt;  // [128 q][64 d] swz (chunk ^ q&7)
#pragma unroll
  for (int fm = 0; fm < 2; ++fm) {
    float rcp = 1.f / lrun[fm];
    int q = w * 32 + fm * 16 + lo;
    int sw = q & 7;
#pragma unroll
    for (int fd = 0; fd < 4; ++fd) {
      int c8 = fd * 2 + (g >> 1);
      f16x4 o4 = {(f16)(oacc[fm][fd][0] * rcp), (f16)(oacc[fm][fd][1] * rcp),
                  (f16)(oacc[fm][fd][2] * rcp), (f16)(oacc[fm][fd][3] * rcp)};
      *(f16x4*)&T2[q * 64 + ((c8 ^ sw) * 8) + (g & 1) * 4] = o4;
    }
  }
  __syncthreads();
  f16* cb = ctxt + (size_t)b * 2048 * 768;
  int qrow = t >> 1, half = t & 1;
#pragma unroll
  for (int c = 0; c < 4; ++c) {
    int c8 = half * 4 + c;
    f16x8 v = *(const f16x8*)&T2[qrow * 64 + ((c8 ^ (qrow & 7)) * 8)];
    *(f16x8*)&cb[(size_t)(n0 + qrow) * 768 + h * 64 + c8 * 8] = v;
  }
}

// ---------------------------------------------------------------- launch
// ws total = 27,525,120 f16 = 52.5 MiB. Ctxt aliases Xt (dead after GEMM1).
extern "C" void kernel_launch(void* const* d_in, const int* in_sizes, int n_in,
                              void* d_out, int out_size, void* d_ws,
                              size_t ws_size, hipStream_t stream) {
  const float* x  = (const float*)d_in[0];
  const float* Wq = (const float*)d_in[1];
  const float* Wk = (const float*)d_in[2];
  const float* Wv = (const float*)d_in[3];
  const float* Wo = (const float*)d_in[4];
  const int* mask = (const int*)d_in[5];
  float* out = (float*)d_out;

  f16* Xt   = (f16*)d_ws;            // 6291456  (B,2048,768) -- reused as Ctxt
  f16* Wcat = Xt + 6291456;          // 1769472  (2304,768)  Wq|Wk|Wv rows
  f16* Wob  = Wcat + 1769472;        // 589824   (768,768)
  f16* QKt  = Wob + 589824;          // 12582912 (B,2048,1536)
  f16* Vbuf = QKt + 12582912;        // 6291456  (B,768,2048)
  f16* Ctxt = Xt;                    // alias    (B,2048,768)

  convert_k<<<576, 256, 0, stream>>>(Wq, Wcat, 589824);
  convert_k<<<576, 256, 0, stream>>>(Wk, Wcat + 589824, 589824);
  convert_k<<<576, 256, 0, stream>>>(Wv, Wcat + 1179648, 589824);
  convert_k<<<576, 256, 0, stream>>>(Wo, Wob, 589824);
  transpose_x<<<dim3(32, 12, 4), 256, 0, stream>>>(x, Xt);
  gemm_kernel<<<dim3(16, 18, 4), 256, 0, stream>>>(Wcat, Xt, QKt, Vbuf, nullptr, 0);
  attn_kernel<<<dim3(16, 48), 256, 0, stream>>>(QKt, Vbuf, mask, Ctxt);
  gemm_kernel<<<dim3(16, 6, 4), 256, 0, stream>>>(Wob, Ctxt, nullptr, nullptr, out, 1);
}

// Round 7
// 237.677 us; speedup vs baseline: 1.4154x; 1.0905x over previous
//
#include <hip/hip_runtime.h>

typedef _Float16 f16;
typedef __attribute__((ext_vector_type(8))) _Float16 f16x8;
typedef __attribute__((ext_vector_type(4))) _Float16 f16x4;
typedef __attribute__((ext_vector_type(4))) float f32x4;

#define DEVINL __device__ __forceinline__

DEVINL void gload16(const void* g, void* l) {
  __builtin_amdgcn_global_load_lds(
      (const __attribute__((address_space(1))) void*)g,
      (__attribute__((address_space(3))) void*)l, 16, 0, 0);
}

DEVINL f32x4 mfma16(f16x8 a, f16x8 b, f32x4 c) {
  return __builtin_amdgcn_mfma_f32_16x16x32_f16(a, b, c, 0, 0, 0);
}

// ---------------------------------------------------------------- converts
// One launch for Wq|Wk|Wv (3 x 589824 into consecutive dst) + Wo separate.
__global__ __launch_bounds__(256) void convert_qkv(const float* __restrict__ wq,
                                                   const float* __restrict__ wk,
                                                   const float* __restrict__ wv,
                                                   f16* __restrict__ dst) {
  int seg = blockIdx.x / 576;
  int i = ((blockIdx.x % 576) * 256 + threadIdx.x) * 4;
  const float* src = seg == 0 ? wq : (seg == 1 ? wk : wv);
  f32x4 v = *(const f32x4*)(src + i);
  f16x4 o = {(f16)v[0], (f16)v[1], (f16)v[2], (f16)v[3]};
  *(f16x4*)(dst + seg * 589824 + i) = o;
}

__global__ __launch_bounds__(256) void convert_k(const float* __restrict__ src,
                                                 f16* __restrict__ dst, int n) {
  int i = (blockIdx.x * 256 + threadIdx.x) * 4;
  if (i + 3 < n) {
    f32x4 v = *(const f32x4*)(src + i);
    f16x4 o = {(f16)v[0], (f16)v[1], (f16)v[2], (f16)v[3]};
    *(f16x4*)(dst + i) = o;
  }
}

// x (B,768,2048) f32 -> Xt (B,2048,768) f16   (64x64 tiles via padded LDS)
__global__ __launch_bounds__(256) void transpose_x(const float* __restrict__ x,
                                                   f16* __restrict__ xt) {
  __shared__ __attribute__((aligned(16))) f16 T[64 * 66];
  const int b = blockIdx.z, c0 = blockIdx.y * 64, n0 = blockIdx.x * 64;
  const int t = threadIdx.x;
  const float* xb = x + (size_t)b * 768 * 2048;
#pragma unroll
  for (int r = 0; r < 4; ++r) {
    int chunk = r * 256 + t;
    int row = chunk >> 4, c4 = (chunk & 15) * 4;
    f32x4 v = *(const f32x4*)&xb[(size_t)(c0 + row) * 2048 + n0 + c4];
#pragma unroll
    for (int e = 0; e < 4; ++e) T[row * 66 + c4 + e] = (f16)v[e];
  }
  __syncthreads();
  f16* xtb = xt + (size_t)b * 2048 * 768;
  int n = t >> 2, cp = (t & 3) * 16;
  __attribute__((aligned(16))) f16 vals[16];
#pragma unroll
  for (int j = 0; j < 16; ++j) vals[j] = T[(cp + j) * 66 + n];
  *(f16x8*)&xtb[(size_t)(n0 + n) * 768 + c0 + cp] = *(const f16x8*)&vals[0];
  *(f16x8*)&xtb[(size_t)(n0 + n) * 768 + c0 + cp + 8] = *(const f16x8*)&vals[8];
}

// ---------------------------------------------------------------- GEMM
// C[m0+128][n0+128] = A(M,768) @ Bt(2048,768)^T   per batch z.
// kind==1: fp32 direct store to outp (B,768,2048)
// kind==0: m0<1536 -> transposed f16 store into qkt (B,2048,1536)
//          m0>=1536 -> direct f16 store into vbuf (B,768,2048)
__global__ __launch_bounds__(256, 2)
void gemm_kernel(const f16* __restrict__ A, const f16* __restrict__ Bt,
                 f16* __restrict__ qkt, f16* __restrict__ vbuf,
                 float* __restrict__ outp, int kind) {
  constexpr int K = 768;
  const int b = blockIdx.z;
  const int n0 = blockIdx.x * 128;
  const int m0 = blockIdx.y * 128;
  const int t = threadIdx.x;
  const int lane = t & 63, w = t >> 6, g = lane >> 4, lo = lane & 15;
  const int wm = (w >> 1) * 64, wn = (w & 1) * 64;

  __shared__ __attribute__((aligned(16))) f16 smem[16384];
  f16* As = smem;          // [128 m][64 k], chunk-swizzled (c8 ^= row&7)
  f16* Bs = smem + 8192;   // [128 n][64 k], same swizzle

  const f16* Ab = A + (size_t)m0 * K;
  const f16* Bb = Bt + (size_t)b * 2048 * K + (size_t)n0 * K;

  const f32x4 zf = {0.f, 0.f, 0.f, 0.f};
  f32x4 acc[4][4];
#pragma unroll
  for (int i = 0; i < 4; ++i)
#pragma unroll
    for (int j = 0; j < 4; ++j) acc[i][j] = zf;

  for (int kt = 0; kt < K; kt += 64) {
    __syncthreads();
#pragma unroll
    for (int r = 0; r < 4; ++r) {
      int chunk = r * 256 + t;
      int row = chunk >> 3;
      int c8 = (chunk & 7) ^ (row & 7);
      gload16(Ab + (size_t)row * K + kt + c8 * 8, As + chunk * 8);
    }
#pragma unroll
    for (int r = 0; r < 4; ++r) {
      int chunk = r * 256 + t;
      int row = chunk >> 3;
      int c8 = (chunk & 7) ^ (row & 7);
      gload16(Bb + (size_t)row * K + kt + c8 * 8, Bs + chunk * 8);
    }
    __syncthreads();
#pragma unroll
    for (int kk = 0; kk < 2; ++kk) {
      f16x8 af[4], bfr[4];
#pragma unroll
      for (int i = 0; i < 4; ++i) {
        int row = wm + i * 16 + lo;
        af[i] = *(const f16x8*)&As[row * 64 + (((kk * 4 + g) ^ (row & 7)) * 8)];
      }
#pragma unroll
      for (int j = 0; j < 4; ++j) {
        int col = wn + j * 16 + lo;
        bfr[j] = *(const f16x8*)&Bs[col * 64 + (((kk * 4 + g) ^ (col & 7)) * 8)];
      }
#pragma unroll
      for (int i = 0; i < 4; ++i)
#pragma unroll
        for (int j = 0; j < 4; ++j)
          acc[i][j] = mfma16(af[i], bfr[j], acc[i][j]);
    }
  }

  if (kind == 1) {
    float* Cb = outp + (size_t)b * 768 * 2048;
#pragma unroll
    for (int i = 0; i < 4; ++i) {
      int row = m0 + wm + i * 16 + g * 4;
#pragma unroll
      for (int j = 0; j < 4; ++j) {
        int col = n0 + wn + j * 16 + lo;
#pragma unroll
        for (int r2 = 0; r2 < 4; ++r2)
          Cb[(size_t)(row + r2) * 2048 + col] = acc[i][j][r2];
      }
    }
  } else if (m0 >= 1536) {
    f16* Vb = vbuf + (size_t)b * 768 * 2048;
#pragma unroll
    for (int i = 0; i < 4; ++i) {
      int row = m0 - 1536 + wm + i * 16 + g * 4;
#pragma unroll
      for (int j = 0; j < 4; ++j) {
        int col = n0 + wn + j * 16 + lo;
#pragma unroll
        for (int r2 = 0; r2 < 4; ++r2)
          Vb[(size_t)(row + r2) * 2048 + col] = (f16)acc[i][j][r2];
      }
    }
  } else {
    // transpose-store via LDS: QKt[b][n0+n][m0 + m] = C[m][n]
    __syncthreads();
    f16* T = smem;  // [128 n][128 m], chunk16-swizzled (c ^= n&15)
#pragma unroll
    for (int i = 0; i < 4; ++i)
#pragma unroll
      for (int j = 0; j < 4; ++j) {
        int nl = wn + j * 16 + lo;
#pragma unroll
        for (int r2 = 0; r2 < 4; ++r2) {
          int ml = wm + i * 16 + g * 4 + r2;
          T[nl * 128 + (((ml >> 3) ^ (nl & 15)) * 8) + (ml & 7)] =
              (f16)acc[i][j][r2];
        }
      }
    __syncthreads();
    f16* Qb = qkt + (size_t)b * 2048 * 1536;
    int n = t >> 1, half = t & 1;
#pragma unroll
    for (int c = 0; c < 8; ++c) {
      int chunk = half * 8 + c;
      f16x8 v = *(const f16x8*)&T[n * 128 + ((chunk ^ (n & 15)) * 8)];
      *(f16x8*)&Qb[(size_t)(n0 + n) * 1536 + m0 + chunk * 8] = v;
    }
  }
}

// ---------------------------------------------------------------- attention
// Round-7: KVBLK=64, K/V DOUBLE-BUFFERED (T3-minimum): issue tile t+1's
// global_load_lds BEFORE computing tile t; ONE barrier per tile whose
// vmcnt-drain lands after ~3K cycles of compute instead of immediately.
// Swapped-operand layout as round 6 (S^T = mfma(K,Q), O^T = mfma(V,P^T)).
// LDS 52KB -> 3 blocks/CU.
__global__ __launch_bounds__(256, 3)
void attn_kernel(const f16* __restrict__ qkt, const f16* __restrict__ vbuf,
                 const int* __restrict__ mask, f16* __restrict__ ctxt) {
  const int bh = blockIdx.y;
  const int b = bh / 12, h = bh % 12;
  const int n0 = blockIdx.x * 128;
  const int t = threadIdx.x;
  const int lane = t & 63, w = t >> 6, g = lane >> 4, lo = lane & 15;

  __shared__ __attribute__((aligned(16))) f16 Kd[2][4096];  // [64 m][64 d] swz
  __shared__ __attribute__((aligned(16))) f16 Vd[2][4096];  // [64 d][64 m] swz
  __shared__ __attribute__((aligned(16))) f16 Ps[4][2048];  // per-wave [32 q][64 m] swz
  __shared__ __attribute__((aligned(16))) f16 bias_s[2048];

  const f16* qb = qkt + (size_t)b * 2048 * 1536;
  const int* mb = mask + b * 2048;
#pragma unroll
  for (int r = 0; r < 8; ++r) {
    int i = r * 256 + t;
    bias_s[i] = (f16)(mb[i] ? 0.f : -60000.f);
  }

  // Q fragments from global; fold 0.125 * log2(e) so exp() -> v_exp_f32.
  constexpr float QS = 0.125f * 1.44269504088896f;
  f16x8 qa[2][2];
#pragma unroll
  for (int fm = 0; fm < 2; ++fm)
#pragma unroll
    for (int kk = 0; kk < 2; ++kk) {
      f16x8 v = *(const f16x8*)&qb[(size_t)(n0 + w * 32 + fm * 16 + lo) * 1536 +
                                   h * 64 + kk * 32 + g * 8];
#pragma unroll
      for (int e = 0; e < 8; ++e) v[e] = (f16)((float)v[e] * QS);
      qa[fm][kk] = v;
    }

  const f32x4 zf = {0.f, 0.f, 0.f, 0.f};
  f32x4 oacc[2][4];
  float mrun[2], lrun[2];
#pragma unroll
  for (int fm = 0; fm < 2; ++fm) {
#pragma unroll
    for (int fd = 0; fd < 4; ++fd) oacc[fm][fd] = zf;
    mrun[fm] = -3e38f;
    lrun[fm] = 0.f;
  }

  const f16* kb_g = qb + 768 + h * 64;
  const f16* vb_g = vbuf + (size_t)b * 768 * 2048 + (size_t)(h * 64) * 2048;
  f16* psw = &Ps[w][0];  // [32 q][64 m], chunk(8xf16)-swizzled c ^= q&7

  // stage tile (64 keys): K 512 chunks + V 512 chunks, 2+2 per thread
#define STAGE_KV(BUF, M0)                                                     \
  {                                                                           \
    _Pragma("unroll") for (int r = 0; r < 2; ++r) {                           \
      int chunk = r * 256 + t;                                                \
      int row = chunk >> 3;                                                   \
      int c8 = (chunk & 7) ^ (row & 7);                                       \
      gload16(kb_g + (size_t)((M0) + row) * 1536 + c8 * 8,                    \
              &Kd[BUF][0] + chunk * 8);                                       \
    }                                                                         \
    _Pragma("unroll") for (int r = 0; r < 2; ++r) {                           \
      int chunk = r * 256 + t;                                                \
      int d = chunk >> 3;                                                     \
      int c8 = (chunk & 7) ^ (d & 7);                                         \
      gload16(vb_g + (size_t)d * 2048 + (M0) + c8 * 8, &Vd[BUF][0] + chunk * 8);\
    }                                                                         \
  }

  STAGE_KV(0, 0);
  __syncthreads();  // drains prologue stage + bias writes

  for (int mt = 0; mt < 32; ++mt) {
    const int cur = mt & 1;
    const int m0 = mt * 64;
    if (mt + 1 < 32) STAGE_KV(cur ^ 1, m0 + 64);  // prefetch next tile

    const f16* Kb = &Kd[cur][0];
    const f16* Vb = &Vd[cur][0];

    // S^T = K Q^T (exp2 domain): sacc[fm][fn][r] = S[q=fm*16+lo][m=fn*16+g*4+r]
    f32x4 sacc[2][4];
#pragma unroll
    for (int fm = 0; fm < 2; ++fm)
#pragma unroll
      for (int fn = 0; fn < 4; ++fn) sacc[fm][fn] = zf;
#pragma unroll
    for (int kk = 0; kk < 2; ++kk)
#pragma unroll
      for (int fn = 0; fn < 4; ++fn) {
        int m = fn * 16 + lo;
        f16x8 kf = *(const f16x8*)&Kb[m * 64 + (((kk * 4 + g) ^ (m & 7)) * 8)];
        sacc[0][fn] = mfma16(kf, qa[0][kk], sacc[0][fn]);
        sacc[1][fn] = mfma16(kf, qa[1][kk], sacc[1][fn]);
      }

    // mask bias: m = fn*16 + g*4 + r -> contiguous f16x4 per fn
#pragma unroll
    for (int fn = 0; fn < 4; ++fn) {
      f16x4 b4 = *(const f16x4*)&bias_s[m0 + fn * 16 + g * 4];
      f32x4 ba = {(float)b4[0], (float)b4[1], (float)b4[2], (float)b4[3]};
      sacc[0][fn] += ba;
      sacc[1][fn] += ba;
    }

    // online softmax: q lane-local; reduce across g only (2 shuffles)
    f16x4 p16[2][4];
#pragma unroll
    for (int fm = 0; fm < 2; ++fm) {
      f32x4 vm = sacc[fm][0];
#pragma unroll
      for (int fn = 1; fn < 4; ++fn)
#pragma unroll
        for (int r = 0; r < 4; ++r) vm[r] = fmaxf(vm[r], sacc[fm][fn][r]);
      float mx = fmaxf(fmaxf(vm[0], vm[1]), fmaxf(vm[2], vm[3]));
      mx = fmaxf(mx, __shfl_xor(mx, 16, 64));
      mx = fmaxf(mx, __shfl_xor(mx, 32, 64));
      float mnew = fmaxf(mrun[fm], mx);
      float alpha = __builtin_amdgcn_exp2f(mrun[fm] - mnew);
      mrun[fm] = mnew;
      f32x4 vs_ = zf;
#pragma unroll
      for (int fn = 0; fn < 4; ++fn) {
        f32x4 pv;
#pragma unroll
        for (int r = 0; r < 4; ++r)
          pv[r] = __builtin_amdgcn_exp2f(sacc[fm][fn][r] - mnew);
        vs_ += pv;
        f16x4 ph = {(f16)pv[0], (f16)pv[1], (f16)pv[2], (f16)pv[3]};
        p16[fm][fn] = ph;
      }
      float rs = (vs_[0] + vs_[1]) + (vs_[2] + vs_[3]);
      rs += __shfl_xor(rs, 16, 64);
      rs += __shfl_xor(rs, 32, 64);
      lrun[fm] = lrun[fm] * alpha + rs;
#pragma unroll
      for (int fd = 0; fd < 4; ++fd) oacc[fm][fd] *= alpha;
    }

    // P -> per-wave LDS (write pos: chunk fn*2+(g>>1), off (g&1)*4  == m=4g+r)
#pragma unroll
    for (int fm = 0; fm < 2; ++fm) {
      int q32 = fm * 16 + lo;
      int sw = q32 & 7;
#pragma unroll
      for (int fn = 0; fn < 4; ++fn) {
        int cq = fn * 2 + (g >> 1);
        *(f16x4*)&psw[q32 * 64 + ((cq ^ sw) * 8) + (g & 1) * 4] = p16[fm][fn];
      }
    }
    // within-wave DS ops stay ordered; no barrier needed
    // O^T += V P^T
#pragma unroll
    for (int kk = 0; kk < 2; ++kk) {
      f16x8 pa[2], vf[4];
#pragma unroll
      for (int fm = 0; fm < 2; ++fm) {
        int q32 = fm * 16 + lo;
        pa[fm] =
            *(const f16x8*)&psw[q32 * 64 + (((kk * 4 + g) ^ (q32 & 7)) * 8)];
      }
#pragma unroll
      for (int fd = 0; fd < 4; ++fd) {
        int d = fd * 16 + lo;
        vf[fd] = *(const f16x8*)&Vb[d * 64 + (((kk * 4 + g) ^ (d & 7)) * 8)];
      }
#pragma unroll
      for (int fm = 0; fm < 2; ++fm)
#pragma unroll
        for (int fd = 0; fd < 4; ++fd)
          oacc[fm][fd] = mfma16(vf[fd], pa[fm], oacc[fm][fd]);
    }

    __syncthreads();  // drains prefetch (next tile ready) + fences buf reuse
  }

  // epilogue: O /= l; oacc quads are d-contiguous -> f16x4 LDS writes
  f16* T2 = &Kd[0][0];  // [128 q][64 d] swz (chunk ^ q&7), overlays Kd+Vd
#pragma unroll
  for (int fm = 0; fm < 2; ++fm) {
    float rcp = 1.f / lrun[fm];
    int q = w * 32 + fm * 16 + lo;
    int sw = q & 7;
#pragma unroll
    for (int fd = 0; fd < 4; ++fd) {
      int c8 = fd * 2 + (g >> 1);
      f16x4 o4 = {(f16)(oacc[fm][fd][0] * rcp), (f16)(oacc[fm][fd][1] * rcp),
                  (f16)(oacc[fm][fd][2] * rcp), (f16)(oacc[fm][fd][3] * rcp)};
      *(f16x4*)&T2[q * 64 + ((c8 ^ sw) * 8) + (g & 1) * 4] = o4;
    }
  }
  __syncthreads();
  f16* cb = ctxt + (size_t)b * 2048 * 768;
  int qrow = t >> 1, half = t & 1;
#pragma unroll
  for (int c = 0; c < 4; ++c) {
    int c8 = half * 4 + c;
    f16x8 v = *(const f16x8*)&T2[qrow * 64 + ((c8 ^ (qrow & 7)) * 8)];
    *(f16x8*)&cb[(size_t)(n0 + qrow) * 768 + h * 64 + c8 * 8] = v;
  }
#undef STAGE_KV
}

// ---------------------------------------------------------------- launch
// ws total = 27,525,120 f16 = 52.5 MiB. Ctxt aliases Xt (dead after GEMM1).
extern "C" void kernel_launch(void* const* d_in, const int* in_sizes, int n_in,
                              void* d_out, int out_size, void* d_ws,
                              size_t ws_size, hipStream_t stream) {
  const float* x  = (const float*)d_in[0];
  const float* Wq = (const float*)d_in[1];
  const float* Wk = (const float*)d_in[2];
  const float* Wv = (const float*)d_in[3];
  const float* Wo = (const float*)d_in[4];
  const int* mask = (const int*)d_in[5];
  float* out = (float*)d_out;

  f16* Xt   = (f16*)d_ws;            // 6291456  (B,2048,768) -- reused as Ctxt
  f16* Wcat = Xt + 6291456;          // 1769472  (2304,768)  Wq|Wk|Wv rows
  f16* Wob  = Wcat + 1769472;        // 589824   (768,768)
  f16* QKt  = Wob + 589824;          // 12582912 (B,2048,1536)
  f16* Vbuf = QKt + 12582912;        // 6291456  (B,768,2048)
  f16* Ctxt = Xt;                    // alias    (B,2048,768)

  convert_qkv<<<1728, 256, 0, stream>>>(Wq, Wk, Wv, Wcat);
  convert_k<<<576, 256, 0, stream>>>(Wo, Wob, 589824);
  transpose_x<<<dim3(32, 12, 4), 256, 0, stream>>>(x, Xt);
  gemm_kernel<<<dim3(16, 18, 4), 256, 0, stream>>>(Wcat, Xt, QKt, Vbuf, nullptr, 0);
  attn_kernel<<<dim3(16, 48), 256, 0, stream>>>(QKt, Vbuf, mask, Ctxt);
  gemm_kernel<<<dim3(16, 6, 4), 256, 0, stream>>>(Wob, Ctxt, nullptr, nullptr, out, 1);
}

// Round 9
// 231.084 us; speedup vs baseline: 1.4558x; 1.0285x over previous
//
#include <hip/hip_runtime.h>

typedef _Float16 f16;
typedef __attribute__((ext_vector_type(8))) _Float16 f16x8;
typedef __attribute__((ext_vector_type(4))) _Float16 f16x4;
typedef __attribute__((ext_vector_type(2))) _Float16 f16x2;
typedef __attribute__((ext_vector_type(4))) float f32x4;

#define DEVINL __device__ __forceinline__

DEVINL void gload16(const void* g, void* l) {
  __builtin_amdgcn_global_load_lds(
      (const __attribute__((address_space(1))) void*)g,
      (__attribute__((address_space(3))) void*)l, 16, 0, 0);
}

DEVINL f32x4 mfma16(f16x8 a, f16x8 b, f32x4 c) {
  return __builtin_amdgcn_mfma_f32_16x16x32_f16(a, b, c, 0, 0, 0);
}

// packed f32x2 -> f16x2 (RTZ); builtin returns __fp16x2, bit-identical layout
DEVINL f16x2 cvt_pk(float a, float b) {
  return __builtin_bit_cast(f16x2, __builtin_amdgcn_cvt_pkrtz(a, b));
}

// ---------------------------------------------------------------- converts
// One launch for Wq|Wk|Wv -> Wcat and Wo -> Wob (4 x 589824 f32 -> f16).
__global__ __launch_bounds__(256) void convert_w(const float* __restrict__ wq,
                                                 const float* __restrict__ wk,
                                                 const float* __restrict__ wv,
                                                 const float* __restrict__ wo,
                                                 f16* __restrict__ wcat,
                                                 f16* __restrict__ wob) {
  int seg = blockIdx.x / 576;
  int i = ((blockIdx.x % 576) * 256 + threadIdx.x) * 4;
  const float* src = seg == 0 ? wq : (seg == 1 ? wk : (seg == 2 ? wv : wo));
  f16* dst = seg < 3 ? wcat + seg * 589824 : wob;
  f32x4 v = *(const f32x4*)(src + i);
  f16x4 o = {(f16)v[0], (f16)v[1], (f16)v[2], (f16)v[3]};
  *(f16x4*)(dst + i) = o;
}

// x (B,768,2048) f32 -> Xt (B,2048,768) f16   (64x64 tiles via padded LDS)
__global__ __launch_bounds__(256) void transpose_x(const float* __restrict__ x,
                                                   f16* __restrict__ xt) {
  __shared__ __attribute__((aligned(16))) f16 T[64 * 66];
  const int b = blockIdx.z, c0 = blockIdx.y * 64, n0 = blockIdx.x * 64;
  const int t = threadIdx.x;
  const float* xb = x + (size_t)b * 768 * 2048;
#pragma unroll
  for (int r = 0; r < 4; ++r) {
    int chunk = r * 256 + t;
    int row = chunk >> 4, c4 = (chunk & 15) * 4;
    f32x4 v = *(const f32x4*)&xb[(size_t)(c0 + row) * 2048 + n0 + c4];
#pragma unroll
    for (int e = 0; e < 4; ++e) T[row * 66 + c4 + e] = (f16)v[e];
  }
  __syncthreads();
  f16* xtb = xt + (size_t)b * 2048 * 768;
  int n = t >> 2, cp = (t & 3) * 16;
  __attribute__((aligned(16))) f16 vals[16];
#pragma unroll
  for (int j = 0; j < 16; ++j) vals[j] = T[(cp + j) * 66 + n];
  *(f16x8*)&xtb[(size_t)(n0 + n) * 768 + c0 + cp] = *(const f16x8*)&vals[0];
  *(f16x8*)&xtb[(size_t)(n0 + n) * 768 + c0 + cp + 8] = *(const f16x8*)&vals[8];
}

// ---------------------------------------------------------------- GEMM
// C[m0+128][n0+128] = A(M,768) @ Bt(2048,768)^T   per batch z.
// kind==1: fp32 direct store to outp (B,768,2048)
// kind==0: m0<1536 -> transposed f16 store into qkt (B,2048,1536)
//          m0>=1536 -> direct f16 store into vbuf (B,768,2048)
__global__ __launch_bounds__(256, 2)
void gemm_kernel(const f16* __restrict__ A, const f16* __restrict__ Bt,
                 f16* __restrict__ qkt, f16* __restrict__ vbuf,
                 float* __restrict__ outp, int kind) {
  constexpr int K = 768;
  const int b = blockIdx.z;
  const int n0 = blockIdx.x * 128;
  const int m0 = blockIdx.y * 128;
  const int t = threadIdx.x;
  const int lane = t & 63, w = t >> 6, g = lane >> 4, lo = lane & 15;
  const int wm = (w >> 1) * 64, wn = (w & 1) * 64;

  __shared__ __attribute__((aligned(16))) f16 smem[16384];
  f16* As = smem;          // [128 m][64 k], chunk-swizzled (c8 ^= row&7)
  f16* Bs = smem + 8192;   // [128 n][64 k], same swizzle

  const f16* Ab = A + (size_t)m0 * K;
  const f16* Bb = Bt + (size_t)b * 2048 * K + (size_t)n0 * K;

  const f32x4 zf = {0.f, 0.f, 0.f, 0.f};
  f32x4 acc[4][4];
#pragma unroll
  for (int i = 0; i < 4; ++i)
#pragma unroll
    for (int j = 0; j < 4; ++j) acc[i][j] = zf;

  for (int kt = 0; kt < K; kt += 64) {
    __syncthreads();
#pragma unroll
    for (int r = 0; r < 4; ++r) {
      int chunk = r * 256 + t;
      int row = chunk >> 3;
      int c8 = (chunk & 7) ^ (row & 7);
      gload16(Ab + (size_t)row * K + kt + c8 * 8, As + chunk * 8);
    }
#pragma unroll
    for (int r = 0; r < 4; ++r) {
      int chunk = r * 256 + t;
      int row = chunk >> 3;
      int c8 = (chunk & 7) ^ (row & 7);
      gload16(Bb + (size_t)row * K + kt + c8 * 8, Bs + chunk * 8);
    }
    __syncthreads();
#pragma unroll
    for (int kk = 0; kk < 2; ++kk) {
      f16x8 af[4], bfr[4];
#pragma unroll
      for (int i = 0; i < 4; ++i) {
        int row = wm + i * 16 + lo;
        af[i] = *(const f16x8*)&As[row * 64 + (((kk * 4 + g) ^ (row & 7)) * 8)];
      }
#pragma unroll
      for (int j = 0; j < 4; ++j) {
        int col = wn + j * 16 + lo;
        bfr[j] = *(const f16x8*)&Bs[col * 64 + (((kk * 4 + g) ^ (col & 7)) * 8)];
      }
#pragma unroll
      for (int i = 0; i < 4; ++i)
#pragma unroll
        for (int j = 0; j < 4; ++j)
          acc[i][j] = mfma16(af[i], bfr[j], acc[i][j]);
    }
  }

  if (kind == 1) {
    float* Cb = outp + (size_t)b * 768 * 2048;
#pragma unroll
    for (int i = 0; i < 4; ++i) {
      int row = m0 + wm + i * 16 + g * 4;
#pragma unroll
      for (int j = 0; j < 4; ++j) {
        int col = n0 + wn + j * 16 + lo;
#pragma unroll
        for (int r2 = 0; r2 < 4; ++r2)
          Cb[(size_t)(row + r2) * 2048 + col] = acc[i][j][r2];
      }
    }
  } else if (m0 >= 1536) {
    f16* Vb = vbuf + (size_t)b * 768 * 2048;
#pragma unroll
    for (int i = 0; i < 4; ++i) {
      int row = m0 - 1536 + wm + i * 16 + g * 4;
#pragma unroll
      for (int j = 0; j < 4; ++j) {
        int col = n0 + wn + j * 16 + lo;
#pragma unroll
        for (int r2 = 0; r2 < 4; ++r2)
          Vb[(size_t)(row + r2) * 2048 + col] = (f16)acc[i][j][r2];
      }
    }
  } else {
    // transpose-store via LDS: QKt[b][n0+n][m0 + m] = C[m][n]
    __syncthreads();
    f16* T = smem;  // [128 n][128 m], chunk16-swizzled (c ^= n&15)
#pragma unroll
    for (int i = 0; i < 4; ++i)
#pragma unroll
      for (int j = 0; j < 4; ++j) {
        int nl = wn + j * 16 + lo;
#pragma unroll
        for (int r2 = 0; r2 < 4; ++r2) {
          int ml = wm + i * 16 + g * 4 + r2;
          T[nl * 128 + (((ml >> 3) ^ (nl & 15)) * 8) + (ml & 7)] =
              (f16)acc[i][j][r2];
        }
      }
    __syncthreads();
    f16* Qb = qkt + (size_t)b * 2048 * 1536;
    int n = t >> 1, half = t & 1;
#pragma unroll
    for (int c = 0; c < 8; ++c) {
      int chunk = half * 8 + c;
      f16x8 v = *(const f16x8*)&T[n * 128 + ((chunk ^ (n & 15)) * 8)];
      *(f16x8*)&Qb[(size_t)(n0 + n) * 1536 + m0 + chunk * 8] = v;
    }
  }
}

// ---------------------------------------------------------------- attention
// Round-9 == round-8 plan with the cvt_pkrtz type fixed via bit_cast:
//  (a) mask bias as MFMA C-INIT (deletes post-QK^T bias adds),
//  (b) T13 defer-max THR=8 (skip alpha/rescale when running max stable),
//  (c) packed cvt_pkrtz for P f32->f16.
// Structure: KVBLK=64, K/V double-buffer, one barrier per tile (round 7).
__global__ __launch_bounds__(256, 3)
void attn_kernel(const f16* __restrict__ qkt, const f16* __restrict__ vbuf,
                 const int* __restrict__ mask, f16* __restrict__ ctxt) {
  const int bh = blockIdx.y;
  const int b = bh / 12, h = bh % 12;
  const int n0 = blockIdx.x * 128;
  const int t = threadIdx.x;
  const int lane = t & 63, w = t >> 6, g = lane >> 4, lo = lane & 15;

  __shared__ __attribute__((aligned(16))) f16 Kd[2][4096];  // [64 m][64 d] swz
  __shared__ __attribute__((aligned(16))) f16 Vd[2][4096];  // [64 d][64 m] swz
  __shared__ __attribute__((aligned(16))) f16 Ps[4][2048];  // per-wave [32 q][64 m] swz
  __shared__ __attribute__((aligned(16))) f16 bias_s[2048];

  const f16* qb = qkt + (size_t)b * 2048 * 1536;
  const int* mb = mask + b * 2048;
#pragma unroll
  for (int r = 0; r < 8; ++r) {
    int i = r * 256 + t;
    bias_s[i] = (f16)(mb[i] ? 0.f : -60000.f);
  }

  // Q fragments from global; fold 0.125 * log2(e) so exp() -> v_exp_f32.
  constexpr float QS = 0.125f * 1.44269504088896f;
  f16x8 qa[2][2];
#pragma unroll
  for (int fm = 0; fm < 2; ++fm)
#pragma unroll
    for (int kk = 0; kk < 2; ++kk) {
      f16x8 v = *(const f16x8*)&qb[(size_t)(n0 + w * 32 + fm * 16 + lo) * 1536 +
                                   h * 64 + kk * 32 + g * 8];
#pragma unroll
      for (int e = 0; e < 8; ++e) v[e] = (f16)((float)v[e] * QS);
      qa[fm][kk] = v;
    }

  const f32x4 zf = {0.f, 0.f, 0.f, 0.f};
  f32x4 oacc[2][4];
  float mrun[2], lrun[2];
#pragma unroll
  for (int fm = 0; fm < 2; ++fm) {
#pragma unroll
    for (int fd = 0; fd < 4; ++fd) oacc[fm][fd] = zf;
    mrun[fm] = -3e38f;
    lrun[fm] = 0.f;
  }

  const f16* kb_g = qb + 768 + h * 64;
  const f16* vb_g = vbuf + (size_t)b * 768 * 2048 + (size_t)(h * 64) * 2048;
  f16* psw = &Ps[w][0];  // [32 q][64 m], chunk(8xf16)-swizzled c ^= q&7

#define STAGE_KV(BUF, M0)                                                     \
  {                                                                           \
    _Pragma("unroll") for (int r = 0; r < 2; ++r) {                           \
      int chunk = r * 256 + t;                                                \
      int row = chunk >> 3;                                                   \
      int c8 = (chunk & 7) ^ (row & 7);                                       \
      gload16(kb_g + (size_t)((M0) + row) * 1536 + c8 * 8,                    \
              &Kd[BUF][0] + chunk * 8);                                       \
    }                                                                         \
    _Pragma("unroll") for (int r = 0; r < 2; ++r) {                           \
      int chunk = r * 256 + t;                                                \
      int d = chunk >> 3;                                                     \
      int c8 = (chunk & 7) ^ (d & 7);                                         \
      gload16(vb_g + (size_t)d * 2048 + (M0) + c8 * 8, &Vd[BUF][0] + chunk * 8);\
    }                                                                         \
  }

  STAGE_KV(0, 0);
  __syncthreads();  // drains prologue stage + bias writes

  for (int mt = 0; mt < 32; ++mt) {
    const int cur = mt & 1;
    const int m0 = mt * 64;
    if (mt + 1 < 32) STAGE_KV(cur ^ 1, m0 + 64);  // prefetch next tile

    const f16* Kb = &Kd[cur][0];
    const f16* Vb = &Vd[cur][0];

    // S^T = K Q^T + bias (bias enters as the MFMA C-initializer)
    f32x4 sacc[2][4];
#pragma unroll
    for (int fn = 0; fn < 4; ++fn) {
      f16x4 b4 = *(const f16x4*)&bias_s[m0 + fn * 16 + g * 4];
      f32x4 ba = {(float)b4[0], (float)b4[1], (float)b4[2], (float)b4[3]};
      sacc[0][fn] = ba;
      sacc[1][fn] = ba;
    }
#pragma unroll
    for (int kk = 0; kk < 2; ++kk)
#pragma unroll
      for (int fn = 0; fn < 4; ++fn) {
        int m = fn * 16 + lo;
        f16x8 kf = *(const f16x8*)&Kb[m * 64 + (((kk * 4 + g) ^ (m & 7)) * 8)];
        sacc[0][fn] = mfma16(kf, qa[0][kk], sacc[0][fn]);
        sacc[1][fn] = mfma16(kf, qa[1][kk], sacc[1][fn]);
      }

    // online softmax with defer-max (T13, THR=8); q = fm*16+lo lane-local
    f16x4 p16[2][4];
#pragma unroll
    for (int fm = 0; fm < 2; ++fm) {
      f32x4 vm = sacc[fm][0];
#pragma unroll
      for (int fn = 1; fn < 4; ++fn)
#pragma unroll
        for (int r = 0; r < 4; ++r) vm[r] = fmaxf(vm[r], sacc[fm][fn][r]);
      float mx = fmaxf(fmaxf(vm[0], vm[1]), fmaxf(vm[2], vm[3]));
      mx = fmaxf(mx, __shfl_xor(mx, 16, 64));
      mx = fmaxf(mx, __shfl_xor(mx, 32, 64));
      if (__any(mx > mrun[fm] + 8.f)) {  // wave-uniform rescale gate
        float mnew = fmaxf(mrun[fm], mx);
        float alpha = __builtin_amdgcn_exp2f(mrun[fm] - mnew);
        mrun[fm] = mnew;
        lrun[fm] *= alpha;
#pragma unroll
        for (int fd = 0; fd < 4; ++fd) oacc[fm][fd] *= alpha;
      }
      float mcur = mrun[fm];
      f32x4 vs_ = zf;
#pragma unroll
      for (int fn = 0; fn < 4; ++fn) {
        f32x4 pv;
#pragma unroll
        for (int r = 0; r < 4; ++r)
          pv[r] = __builtin_amdgcn_exp2f(sacc[fm][fn][r] - mcur);
        vs_ += pv;
        f16x2 plo = cvt_pk(pv[0], pv[1]);
        f16x2 phi = cvt_pk(pv[2], pv[3]);
        f16x4 ph = {plo[0], plo[1], phi[0], phi[1]};
        p16[fm][fn] = ph;
      }
      float rs = (vs_[0] + vs_[1]) + (vs_[2] + vs_[3]);
      rs += __shfl_xor(rs, 16, 64);
      rs += __shfl_xor(rs, 32, 64);
      lrun[fm] += rs;
    }

    // P -> per-wave LDS (write pos: chunk fn*2+(g>>1), off (g&1)*4  == m=4g+r)
#pragma unroll
    for (int fm = 0; fm < 2; ++fm) {
      int q32 = fm * 16 + lo;
      int sw = q32 & 7;
#pragma unroll
      for (int fn = 0; fn < 4; ++fn) {
        int cq = fn * 2 + (g >> 1);
        *(f16x4*)&psw[q32 * 64 + ((cq ^ sw) * 8) + (g & 1) * 4] = p16[fm][fn];
      }
    }
    // within-wave DS ops stay ordered; no barrier needed
    // O^T += V P^T
#pragma unroll
    for (int kk = 0; kk < 2; ++kk) {
      f16x8 pa[2], vf[4];
#pragma unroll
      for (int fm = 0; fm < 2; ++fm) {
        int q32 = fm * 16 + lo;
        pa[fm] =
            *(const f16x8*)&psw[q32 * 64 + (((kk * 4 + g) ^ (q32 & 7)) * 8)];
      }
#pragma unroll
      for (int fd = 0; fd < 4; ++fd) {
        int d = fd * 16 + lo;
        vf[fd] = *(const f16x8*)&Vb[d * 64 + (((kk * 4 + g) ^ (d & 7)) * 8)];
      }
#pragma unroll
      for (int fm = 0; fm < 2; ++fm)
#pragma unroll
        for (int fd = 0; fd < 4; ++fd)
          oacc[fm][fd] = mfma16(vf[fd], pa[fm], oacc[fm][fd]);
    }

    __syncthreads();  // drains prefetch (next tile ready) + fences buf reuse
  }

  // epilogue: O /= l; oacc quads are d-contiguous -> f16x4 LDS writes
  f16* T2 = &Kd[0][0];  // [128 q][64 d] swz (chunk ^ q&7), overlays Kd+Vd
#pragma unroll
  for (int fm = 0; fm < 2; ++fm) {
    float rcp = 1.f / lrun[fm];
    int q = w * 32 + fm * 16 + lo;
    int sw = q & 7;
#pragma unroll
    for (int fd = 0; fd < 4; ++fd) {
      int c8 = fd * 2 + (g >> 1);
      f16x4 o4 = {(f16)(oacc[fm][fd][0] * rcp), (f16)(oacc[fm][fd][1] * rcp),
                  (f16)(oacc[fm][fd][2] * rcp), (f16)(oacc[fm][fd][3] * rcp)};
      *(f16x4*)&T2[q * 64 + ((c8 ^ sw) * 8) + (g & 1) * 4] = o4;
    }
  }
  __syncthreads();
  f16* cb = ctxt + (size_t)b * 2048 * 768;
  int qrow = t >> 1, half = t & 1;
#pragma unroll
  for (int c = 0; c < 4; ++c) {
    int c8 = half * 4 + c;
    f16x8 v = *(const f16x8*)&T2[qrow * 64 + ((c8 ^ (qrow & 7)) * 8)];
    *(f16x8*)&cb[(size_t)(n0 + qrow) * 768 + h * 64 + c8 * 8] = v;
  }
#undef STAGE_KV
}

// ---------------------------------------------------------------- launch
// ws total = 27,525,120 f16 = 52.5 MiB. Ctxt aliases Xt (dead after GEMM1).
extern "C" void kernel_launch(void* const* d_in, const int* in_sizes, int n_in,
                              void* d_out, int out_size, void* d_ws,
                              size_t ws_size, hipStream_t stream) {
  const float* x  = (const float*)d_in[0];
  const float* Wq = (const float*)d_in[1];
  const float* Wk = (const float*)d_in[2];
  const float* Wv = (const float*)d_in[3];
  const float* Wo = (const float*)d_in[4];
  const int* mask = (const int*)d_in[5];
  float* out = (float*)d_out;

  f16* Xt   = (f16*)d_ws;            // 6291456  (B,2048,768) -- reused as Ctxt
  f16* Wcat = Xt + 6291456;          // 1769472  (2304,768)  Wq|Wk|Wv rows
  f16* Wob  = Wcat + 1769472;        // 589824   (768,768)
  f16* QKt  = Wob + 589824;          // 12582912 (B,2048,1536)
  f16* Vbuf = QKt + 12582912;        // 6291456  (B,768,2048)
  f16* Ctxt = Xt;                    // alias    (B,2048,768)

  convert_w<<<2304, 256, 0, stream>>>(Wq, Wk, Wv, Wo, Wcat, Wob);
  transpose_x<<<dim3(32, 12, 4), 256, 0, stream>>>(x, Xt);
  gemm_kernel<<<dim3(16, 18, 4), 256, 0, stream>>>(Wcat, Xt, QKt, Vbuf, nullptr, 0);
  attn_kernel<<<dim3(16, 48), 256, 0, stream>>>(QKt, Vbuf, mask, Ctxt);
  gemm_kernel<<<dim3(16, 6, 4), 256, 0, stream>>>(Wob, Ctxt, nullptr, nullptr, out, 1);
}